// Round 3
// baseline (80.568 us; speedup 1.0000x reference)
//
#include <hip/hip_runtime.h>
#include <hip/hip_bf16.h>
#include <math.h>

typedef __attribute__((ext_vector_type(8))) __bf16 bf16x8;
typedef __attribute__((ext_vector_type(4))) float  f32x4;

constexpr int NN   = 2048;  // points per batch
constexpr int DD   = 128;   // dim
constexpr int TI   = 128;   // i-tile rows per block
constexpr int TJ   = 64;    // j-tile rows
constexpr int NJI  = 4;     // j-tiles per block (persistent over 256 cols)
constexpr int ROWB = 256;   // bytes per bf16 row (128 * 2)

__device__ __forceinline__ void gload_lds16(const void* g, void* l) {
    __builtin_amdgcn_global_load_lds(
        (const __attribute__((address_space(1))) void*)g,
        (__attribute__((address_space(3))) void*)l, 16, 0, 0);
}

__device__ __forceinline__ float fast_sqrt(float v) {
#if __has_builtin(__builtin_amdgcn_sqrtf)
    return __builtin_amdgcn_sqrtf(v);   // v_sqrt_f32, ~1 ulp; absmax tol is 0.125
#else
    return sqrtf(v);
#endif
}

// ============================================================================
// Prep: fp32 x -> bf16, XOR-swizzled rows (byte ^= (row&7)<<4) so main can
// global_load_lds linearly and ds_read_b128 conflict-free. Norms from the
// bf16-ROUNDED values so the diagonal cancels like the reference.
// ============================================================================
__global__ __launch_bounds__(256)
void edm_prep(const float* __restrict__ x, __bf16* __restrict__ xb,
              float* __restrict__ sq) {
    const int t  = threadIdx.x;
    const int rl = t >> 4;
    const int c  = t & 15;
    const int g  = blockIdx.x * 16 + rl;   // global row (= b*2048 + n)

    const float4* p = (const float4*)(x + (size_t)g * DD + c * 8);
    const float4 v0 = p[0];
    const float4 v1 = p[1];
    bf16x8 w;
    w[0] = (__bf16)v0.x; w[1] = (__bf16)v0.y;
    w[2] = (__bf16)v0.z; w[3] = (__bf16)v0.w;
    w[4] = (__bf16)v1.x; w[5] = (__bf16)v1.y;
    w[6] = (__bf16)v1.z; w[7] = (__bf16)v1.w;

    float s = 0.f;
    #pragma unroll
    for (int j = 0; j < 8; ++j) { const float f = (float)w[j]; s += f * f; }

    const int byte = (c * 16) ^ ((g & 7) << 4);
    *(bf16x8*)((char*)xb + (size_t)g * ROWB + byte) = w;

    s += __shfl_xor(s, 1);
    s += __shfl_xor(s, 2);
    s += __shfl_xor(s, 4);
    s += __shfl_xor(s, 8);
    if (c == 0) sq[g] = s;
}

// ============================================================================
// Main: 512 blocks = exactly 2/CU (all resident, no tail). Each block stages
// A once, holds 16 A-frags in registers, loops 4 j-tiles with double-buffered
// B staging. T4 loop discipline: counted s_waitcnt vmcnt(8) + raw s_barrier —
// the epilogue stores are NEVER drained inside the loop (they retire async
// under later iterations and flush at endpgm).
//
// Per-wave VMEM queue at the iter-jj wait point (program order, FIFO):
//   [4 x gload_lds for B(jj)]  [8 x global_store_dwordx4 from iter jj-1]
// -> vmcnt(8) drains exactly the 4 B(jj) loads, leaves the stores in flight.
// ============================================================================
__global__ __launch_bounds__(256, 2)
void edm_main(const __bf16* __restrict__ xb, const float* __restrict__ sq,
              float* __restrict__ out) {
    __shared__ __align__(16) char As[TI * ROWB];        // 32 KB
    __shared__ __align__(16) char Bs[2][TJ * ROWB];     // 2 x 16 KB

    const int t = threadIdx.x;
    // XCD-chunked bijective swizzle (nwg=512, 512%8==0).
    const int bid = blockIdx.x + (blockIdx.y << 3) + (blockIdx.z << 7);
    const int w   = ((bid & 7) << 6) + (bid >> 3);
    const int jg  = w & 7;          // j-group: 4 tiles of 64 -> cols jg*256..
    const int it  = (w >> 3) & 15;  // i-tile
    const int b   = w >> 7;         // batch

    const char* xbase = (const char*)xb + (size_t)b * NN * ROWB;
    const char* srcA  = xbase + (size_t)it * TI * ROWB;
    const char* srcB  = xbase + (size_t)(jg * NJI) * TJ * ROWB;

    // ---- stage A (32 KB) + B0 (16 KB), async; drained once by __syncthreads
    #pragma unroll
    for (int i = 0; i < 8; ++i) {
        const int off = (t + i * 256) * 16;
        gload_lds16(srcA + off, As + off);
    }
    #pragma unroll
    for (int i = 0; i < 4; ++i) {
        const int off = (t + i * 256) * 16;
        gload_lds16(srcB + off, (char*)Bs[0] + off);
    }

    const int wave = t >> 6;
    const int lane = t & 63;
    const int wm = (wave >> 1) * 64;
    const int wn = (wave & 1) * 32;
    const int lm = lane & 15;
    const int q  = lane >> 4;
    const int swz = (lm & 7) << 4;

    // ---- hoist ALL scalar-norm loads above the full drain so they never
    // appear in the in-loop vmcnt bookkeeping.
    const float* sqi  = sq + b * NN + it * TI;
    const float* sqj0 = sq + b * NN + jg * NJI * TJ;
    float si[4];
    #pragma unroll
    for (int mf = 0; mf < 4; ++mf) si[mf] = sqi[wm + mf * 16 + lm];
    f32x4 sj_all[NJI][2];
    #pragma unroll
    for (int jj = 0; jj < NJI; ++jj)
        #pragma unroll
        for (int nf = 0; nf < 2; ++nf)
            sj_all[jj][nf] = *(const f32x4*)(sqj0 + jj * TJ + wn + nf * 16 + q * 4);

    __syncthreads();   // ONE full vmcnt(0) drain: As + Bs[0] + norms resident

    // ---- hoist A fragments: invariant across all 4 j-tiles (64 VGPRs)
    bf16x8 a[4][4];
    #pragma unroll
    for (int ks = 0; ks < 4; ++ks) {
        const int cb = ks * 64 + q * 16;
        #pragma unroll
        for (int mf = 0; mf < 4; ++mf)
            a[ks][mf] = *(const bf16x8*)(As + (wm + mf * 16 + lm) * ROWB + (cb ^ swz));
    }

    float* outb = out + ((size_t)b * NN + (size_t)it * TI) * NN
                      + (size_t)(jg * NJI) * TJ;

    #pragma unroll
    for (int jj = 0; jj < NJI; ++jj) {
        if (jj > 0) {
            // drain exactly the 4 B(jj) gload_lds (8 newer stores stay in flight)
            asm volatile("s_waitcnt vmcnt(8)" ::: "memory");
            __builtin_amdgcn_s_barrier();   // publish all waves' LDS loads
        }
        // prefetch B[jj+1] into the other buffer. Clobber-safe: that buffer
        // held B[jj-1], whose reads completed before the barrier above.
        if (jj + 1 < NJI) {
            const char* nsrc = srcB + (size_t)(jj + 1) * TJ * ROWB;
            char* ndst = (char*)Bs[(jj + 1) & 1];
            #pragma unroll
            for (int i = 0; i < 4; ++i) {
                const int off = (t + i * 256) * 16;
                gload_lds16(nsrc + off, ndst + off);
            }
        }

        const char* Bcur = (const char*)Bs[jj & 1];
        f32x4 acc[4][2] = {};
        #pragma unroll
        for (int ks = 0; ks < 4; ++ks) {
            const int cb = ks * 64 + q * 16;
            bf16x8 bb[2];
            #pragma unroll
            for (int nf = 0; nf < 2; ++nf)
                bb[nf] = *(const bf16x8*)(Bcur + (wn + nf * 16 + lm) * ROWB + (cb ^ swz));
            #pragma unroll
            for (int mf = 0; mf < 4; ++mf)
                #pragma unroll
                for (int nf = 0; nf < 2; ++nf)
                    acc[mf][nf] = __builtin_amdgcn_mfma_f32_16x16x32_bf16(
                        bb[nf], a[ks][mf], acc[mf][nf], 0, 0, 0);
        }

        // ---- epilogue: d = sqrt(max(si + sj - 2*cross, 0) + eps), 16B stores.
        // Exactly 8 global_store_dwordx4 per lane per iter (vmcnt accounting).
        #pragma unroll
        for (int mf = 0; mf < 4; ++mf) {
            const int i = wm + mf * 16 + lm;
            float* rowp = outb + (size_t)i * NN + jj * TJ;
            #pragma unroll
            for (int nf = 0; nf < 2; ++nf) {
                f32x4 d;
                #pragma unroll
                for (int r = 0; r < 4; ++r) {
                    float d2 = si[mf] + sj_all[jj][nf][r] - 2.0f * acc[mf][nf][r];
                    d[r] = fast_sqrt(fmaxf(d2, 0.0f) + 1e-7f);
                }
                *(f32x4*)(rowp + wn + nf * 16 + q * 4) = d;
            }
        }
    }
}

extern "C" void kernel_launch(void* const* d_in, const int* in_sizes, int n_in,
                              void* d_out, int out_size, void* d_ws, size_t ws_size,
                              hipStream_t stream) {
    const float* x = (const float*)d_in[0];
    float* out = (float*)d_out;
    float*  sqw = (float*)d_ws;                       // 8192 f32
    __bf16* xbw = (__bf16*)((char*)d_ws + 32768);     // 2 MB bf16, swizzled
    edm_prep<<<dim3((4 * NN) / 16), dim3(256), 0, stream>>>(x, xbw, sqw);
    edm_main<<<dim3(NN / (TJ * NJI), NN / TI, 4), dim3(256), 0, stream>>>(xbw, sqw, out);
}